// Round 5
// baseline (57.113 us; speedup 1.0000x reference)
//
#include <hip/hip_runtime.h>
#include <hip/hip_bf16.h>
#include <math.h>

#define NCC 20
#define NQQ 27
#define BSZ 8192
#define NPAIR (BSZ * NCC)

__device__ __forceinline__ float frcp(float x) { return __builtin_amdgcn_rcpf(x); }

struct Tgt {
    float tc0, tc1, tc2, tw, th, td;
    float tl0, tl1, tl2, th0, th1, th2, vol;
};

__device__ __forceinline__ Tgt make_tgt(float2 t01, float2 t23, float2 t45) {
    Tgt T;
    T.tc0 = t01.x; T.tc1 = t01.y; T.tc2 = t23.x;
    T.tw  = t23.y; T.th  = t45.x; T.td  = t45.y;
    T.tl0 = T.tc0 - 0.5f * T.tw; T.tl1 = T.tc1 - 0.5f * T.th; T.tl2 = T.tc2 - 0.5f * T.td;
    T.th0 = T.tc0 + 0.5f * T.tw; T.th1 = T.tc1 + 0.5f * T.th; T.th2 = T.tc2 + 0.5f * T.td;
    T.vol = (T.th0 - T.tl0) * (T.th1 - T.tl1) * (T.th2 - T.tl2);
    return T;
}

__device__ __forceinline__ float pair_cost(float2 b01, float2 b23, float2 b45,
                                           float lg, const Tgt& T, float* cg) {
    const float bc0 = b01.x, bc1 = b01.y, bc2 = b23.x;
    const float bw  = b23.y, bh  = b45.x, bd  = b45.y;

    // -sigmoid via v_rcp_f32 (1 ulp) instead of IEEE divide
    const float cost_class = -frcp(1.0f + __expf(-lg));

    const float cost_bbox =
        fabsf(bc0 - T.tc0) + fabsf(bc1 - T.tc1) + fabsf(bc2 - T.tc2) +
        fabsf(bw  - T.tw ) + fabsf(bh  - T.th ) + fabsf(bd  - T.td );

    const float cc0 = fmaxf(bc0, 0.0f), cc1 = fmaxf(bc1, 0.0f), cc2 = fmaxf(bc2, 0.0f);
    const float cw  = fmaxf(bw , 0.0f), ch  = fmaxf(bh , 0.0f), cd  = fmaxf(bd , 0.0f);
    const float pl0 = cc0 - 0.5f * cw, pl1 = cc1 - 0.5f * ch, pl2 = cc2 - 0.5f * cd;
    const float ph0 = cc0 + 0.5f * cw, ph1 = cc1 + 0.5f * ch, ph2 = cc2 + 0.5f * cd;
    const float vol_p = (ph0 - pl0) * (ph1 - pl1) * (ph2 - pl2);

    const float i0 = fmaxf(fminf(ph0, T.th0) - fmaxf(pl0, T.tl0), 0.0f);
    const float i1 = fmaxf(fminf(ph1, T.th1) - fmaxf(pl1, T.tl1), 0.0f);
    const float i2 = fmaxf(fminf(ph2, T.th2) - fmaxf(pl2, T.tl2), 0.0f);
    const float inter = i0 * i1 * i2;
    const float uni   = vol_p + T.vol - inter;
    const float iou   = inter * frcp(uni);

    const float h0 = fmaxf(fmaxf(ph0, T.th0) - fminf(pl0, T.tl0), 0.0f);
    const float h1 = fmaxf(fmaxf(ph1, T.th1) - fminf(pl1, T.tl1), 0.0f);
    const float h2 = fmaxf(fmaxf(ph2, T.th2) - fminf(pl2, T.tl2), 0.0f);
    const float hull = h0 * h1 * h2;

    const float giou = iou - (hull - uni) * frcp(hull);
    *cg = -giou;
    return 5.0f * cost_bbox + 2.0f * cost_class + 2.0f * (-giou);
}

// 8 lanes per pair; lane l handles queries 4l..4l+3 (block-contiguous -> ballot
// tie-break == stable top_k). 8 pairs per wave, 32 per block.
__global__ __launch_bounds__(256, 8) void matcher_kernel(
    const float* __restrict__ logits,
    const float* __restrict__ boxes,
    const float* __restrict__ tboxes,
    const int*   __restrict__ present,
    float* __restrict__ out_matches,
    float* __restrict__ out_soft)
{
    const int tid = blockIdx.x * blockDim.x + threadIdx.x;
    const int p   = tid >> 3;
    const int l   = tid & 7;
    const int q0  = l * 4;

    const int qa = (q0 + 0 < NQQ) ? q0 + 0 : NQQ - 1;
    const int qb = (q0 + 1 < NQQ) ? q0 + 1 : NQQ - 1;
    const int qc = (q0 + 2 < NQQ) ? q0 + 2 : NQQ - 1;
    const int qd = (q0 + 3 < NQQ) ? q0 + 3 : NQQ - 1;

    // ---- issue ALL loads up front ----
    const float* bp = boxes + (size_t)p * (NQQ * 6);
    float2 a01 = *reinterpret_cast<const float2*>(bp + qa * 6 + 0);
    float2 a23 = *reinterpret_cast<const float2*>(bp + qa * 6 + 2);
    float2 a45 = *reinterpret_cast<const float2*>(bp + qa * 6 + 4);
    float2 b01 = *reinterpret_cast<const float2*>(bp + qb * 6 + 0);
    float2 b23 = *reinterpret_cast<const float2*>(bp + qb * 6 + 2);
    float2 b45 = *reinterpret_cast<const float2*>(bp + qb * 6 + 4);
    float2 c01 = *reinterpret_cast<const float2*>(bp + qc * 6 + 0);
    float2 c23 = *reinterpret_cast<const float2*>(bp + qc * 6 + 2);
    float2 c45 = *reinterpret_cast<const float2*>(bp + qc * 6 + 4);
    float2 d01 = *reinterpret_cast<const float2*>(bp + qd * 6 + 0);
    float2 d23 = *reinterpret_cast<const float2*>(bp + qd * 6 + 2);
    float2 d45 = *reinterpret_cast<const float2*>(bp + qd * 6 + 4);
    const float* lp = logits + (size_t)p * NQQ;
    const float lga = lp[qa], lgb = lp[qb], lgc = lp[qc], lgd = lp[qd];
    const float* t = tboxes + (size_t)p * 6;
    float2 t01 = *reinterpret_cast<const float2*>(t + 0);
    float2 t23 = *reinterpret_cast<const float2*>(t + 2);
    float2 t45 = *reinterpret_cast<const float2*>(t + 4);
    const int pres = present[p];

    const Tgt T = make_tgt(t01, t23, t45);

    const bool va = (q0 + 0 < NQQ), vb = (q0 + 1 < NQQ),
               vc = (q0 + 2 < NQQ), vd = (q0 + 3 < NQQ);

    float cg0, cg1, cg2, cg3;
    float C0 = pair_cost(a01, a23, a45, lga, T, &cg0);
    float C1 = pair_cost(b01, b23, b45, lgb, T, &cg1);
    float C2 = pair_cost(c01, c23, c45, lgc, T, &cg2);
    float C3 = pair_cost(d01, d23, d45, lgd, T, &cg3);
    if (!va) C0 = INFINITY;
    if (!vb) C1 = INFINITY;
    if (!vc) C2 = INFINITY;
    if (!vd) C3 = INFINITY;

    // ---- local reductions (ascending strict < => lowest local q on tie) ----
    float bestC = C0; int bestj = 0;
    if (C1 < bestC) { bestC = C1; bestj = 1; }
    if (C2 < bestC) { bestC = C2; bestj = 2; }
    if (C3 < bestC) { bestC = C3; bestj = 3; }
    float gx = va ? cg0 : -INFINITY;
    float gn = va ? cg0 :  INFINITY;
    if (vb) { gx = fmaxf(gx, cg1); gn = fminf(gn, cg1); }
    if (vc) { gx = fmaxf(gx, cg2); gn = fminf(gn, cg2); }
    if (vd) { gx = fmaxf(gx, cg3); gn = fminf(gn, cg3); }

    // ---- 3-step butterfly over the 8-lane group ----
    float m = bestC;
#pragma unroll
    for (int s = 4; s >= 1; s >>= 1) {
        m  = fminf(m,  __shfl_xor(m,  s, 8));
        gx = fmaxf(gx, __shfl_xor(gx, s, 8));
        gn = fminf(gn, __shfl_xor(gn, s, 8));
    }

    // ---- argmin winner via ballot: lowest lane w/ local min == m ----
    const unsigned long long bal = __ballot(bestC == m);
    const int gbase  = (threadIdx.x & 63) & ~7;
    const unsigned int gbits = (unsigned int)(bal >> gbase) & 0xFFu;
    const int winner = __ffs(gbits) - 1;
    const bool mine  = (winner == l);

    // ---- outputs: nontemporal (no-allocate) coalesced stores ----
    float* om = out_matches + (size_t)p * NQQ + q0;
    float* os = out_soft    + (size_t)p * NQQ + q0;
    const float inv = frcp(gn - gx);
    if (va) { __builtin_nontemporal_store((pres && mine && bestj == 0) ? 1.0f : 0.0f, om + 0);
              __builtin_nontemporal_store(pres ? fmaxf((cg0 - gx) * inv, 0.0f) : -1.0f, os + 0); }
    if (vb) { __builtin_nontemporal_store((pres && mine && bestj == 1) ? 1.0f : 0.0f, om + 1);
              __builtin_nontemporal_store(pres ? fmaxf((cg1 - gx) * inv, 0.0f) : -1.0f, os + 1); }
    if (vc) { __builtin_nontemporal_store((pres && mine && bestj == 2) ? 1.0f : 0.0f, om + 2);
              __builtin_nontemporal_store(pres ? fmaxf((cg2 - gx) * inv, 0.0f) : -1.0f, os + 2); }
    if (vd) { __builtin_nontemporal_store((pres && mine && bestj == 3) ? 1.0f : 0.0f, om + 3);
              __builtin_nontemporal_store(pres ? fmaxf((cg3 - gx) * inv, 0.0f) : -1.0f, os + 3); }
}

extern "C" void kernel_launch(void* const* d_in, const int* in_sizes, int n_in,
                              void* d_out, int out_size, void* d_ws, size_t ws_size,
                              hipStream_t stream) {
    const float* logits  = (const float*)d_in[0];
    const float* boxes   = (const float*)d_in[1];
    const float* tboxes  = (const float*)d_in[2];
    const int*   presnt  = (const int*)d_in[3];

    float* out = (float*)d_out;
    float* out_matches = out;
    float* out_soft    = out + (size_t)NPAIR * NQQ;

    dim3 block(256);
    dim3 grid((NPAIR * 8) / 256);   // exactly 5120 blocks
    matcher_kernel<<<grid, block, 0, stream>>>(logits, boxes, tboxes, presnt,
                                               out_matches, out_soft);
}

// Round 6
// 34.895 us; speedup vs baseline: 1.6367x; 1.6367x over previous
//
#include <hip/hip_runtime.h>
#include <hip/hip_bf16.h>
#include <math.h>

#define NCC 20
#define NQQ 27
#define BSZ 8192
#define NPAIR (BSZ * NCC)

__device__ __forceinline__ float frcp(float x) { return __builtin_amdgcn_rcpf(x); }

struct Tgt {
    float tc0, tc1, tc2, tw, th, td;
    float tl0, tl1, tl2, th0, th1, th2, vol;
};

__device__ __forceinline__ Tgt make_tgt(float2 t01, float2 t23, float2 t45) {
    Tgt T;
    T.tc0 = t01.x; T.tc1 = t01.y; T.tc2 = t23.x;
    T.tw  = t23.y; T.th  = t45.x; T.td  = t45.y;
    T.tl0 = T.tc0 - 0.5f * T.tw; T.tl1 = T.tc1 - 0.5f * T.th; T.tl2 = T.tc2 - 0.5f * T.td;
    T.th0 = T.tc0 + 0.5f * T.tw; T.th1 = T.tc1 + 0.5f * T.th; T.th2 = T.tc2 + 0.5f * T.td;
    T.vol = (T.th0 - T.tl0) * (T.th1 - T.tl1) * (T.th2 - T.tl2);
    return T;
}

__device__ __forceinline__ float pair_cost(float2 b01, float2 b23, float2 b45,
                                           float lg, const Tgt& T, float* cg) {
    const float bc0 = b01.x, bc1 = b01.y, bc2 = b23.x;
    const float bw  = b23.y, bh  = b45.x, bd  = b45.y;

    // -sigmoid via v_rcp_f32 (1 ulp) instead of IEEE divide
    const float cost_class = -frcp(1.0f + __expf(-lg));

    const float cost_bbox =
        fabsf(bc0 - T.tc0) + fabsf(bc1 - T.tc1) + fabsf(bc2 - T.tc2) +
        fabsf(bw  - T.tw ) + fabsf(bh  - T.th ) + fabsf(bd  - T.td );

    const float cc0 = fmaxf(bc0, 0.0f), cc1 = fmaxf(bc1, 0.0f), cc2 = fmaxf(bc2, 0.0f);
    const float cw  = fmaxf(bw , 0.0f), ch  = fmaxf(bh , 0.0f), cd  = fmaxf(bd , 0.0f);
    const float pl0 = cc0 - 0.5f * cw, pl1 = cc1 - 0.5f * ch, pl2 = cc2 - 0.5f * cd;
    const float ph0 = cc0 + 0.5f * cw, ph1 = cc1 + 0.5f * ch, ph2 = cc2 + 0.5f * cd;
    const float vol_p = (ph0 - pl0) * (ph1 - pl1) * (ph2 - pl2);

    const float i0 = fmaxf(fminf(ph0, T.th0) - fmaxf(pl0, T.tl0), 0.0f);
    const float i1 = fmaxf(fminf(ph1, T.th1) - fmaxf(pl1, T.tl1), 0.0f);
    const float i2 = fmaxf(fminf(ph2, T.th2) - fmaxf(pl2, T.tl2), 0.0f);
    const float inter = i0 * i1 * i2;
    const float uni   = vol_p + T.vol - inter;
    const float iou   = inter * frcp(uni);

    const float h0 = fmaxf(fmaxf(ph0, T.th0) - fminf(pl0, T.tl0), 0.0f);
    const float h1 = fmaxf(fmaxf(ph1, T.th1) - fminf(pl1, T.tl1), 0.0f);
    const float h2 = fmaxf(fmaxf(ph2, T.th2) - fminf(pl2, T.tl2), 0.0f);
    const float hull = h0 * h1 * h2;

    const float giou = iou - (hull - uni) * frcp(hull);
    *cg = -giou;
    return 5.0f * cost_bbox + 2.0f * cost_class + 2.0f * (-giou);
}

// 8 lanes per pair; lane l handles queries 4l..4l+3 (block-contiguous -> ballot
// tie-break == stable top_k). 8 pairs per wave, 32 per block.
__global__ __launch_bounds__(256, 8) void matcher_kernel(
    const float* __restrict__ logits,
    const float* __restrict__ boxes,
    const float* __restrict__ tboxes,
    const int*   __restrict__ present,
    float* __restrict__ out_matches,
    float* __restrict__ out_soft)
{
    const int tid = blockIdx.x * blockDim.x + threadIdx.x;
    const int p   = tid >> 3;
    const int l   = tid & 7;
    const int q0  = l * 4;

    const int qa = (q0 + 0 < NQQ) ? q0 + 0 : NQQ - 1;
    const int qb = (q0 + 1 < NQQ) ? q0 + 1 : NQQ - 1;
    const int qc = (q0 + 2 < NQQ) ? q0 + 2 : NQQ - 1;
    const int qd = (q0 + 3 < NQQ) ? q0 + 3 : NQQ - 1;

    // ---- issue ALL loads up front ----
    const float* bp = boxes + (size_t)p * (NQQ * 6);
    float2 a01 = *reinterpret_cast<const float2*>(bp + qa * 6 + 0);
    float2 a23 = *reinterpret_cast<const float2*>(bp + qa * 6 + 2);
    float2 a45 = *reinterpret_cast<const float2*>(bp + qa * 6 + 4);
    float2 b01 = *reinterpret_cast<const float2*>(bp + qb * 6 + 0);
    float2 b23 = *reinterpret_cast<const float2*>(bp + qb * 6 + 2);
    float2 b45 = *reinterpret_cast<const float2*>(bp + qb * 6 + 4);
    float2 c01 = *reinterpret_cast<const float2*>(bp + qc * 6 + 0);
    float2 c23 = *reinterpret_cast<const float2*>(bp + qc * 6 + 2);
    float2 c45 = *reinterpret_cast<const float2*>(bp + qc * 6 + 4);
    float2 d01 = *reinterpret_cast<const float2*>(bp + qd * 6 + 0);
    float2 d23 = *reinterpret_cast<const float2*>(bp + qd * 6 + 2);
    float2 d45 = *reinterpret_cast<const float2*>(bp + qd * 6 + 4);
    const float* lp = logits + (size_t)p * NQQ;
    const float lga = lp[qa], lgb = lp[qb], lgc = lp[qc], lgd = lp[qd];
    const float* t = tboxes + (size_t)p * 6;
    float2 t01 = *reinterpret_cast<const float2*>(t + 0);
    float2 t23 = *reinterpret_cast<const float2*>(t + 2);
    float2 t45 = *reinterpret_cast<const float2*>(t + 4);
    const int pres = present[p];

    const Tgt T = make_tgt(t01, t23, t45);

    const bool va = (q0 + 0 < NQQ), vb = (q0 + 1 < NQQ),
               vc = (q0 + 2 < NQQ), vd = (q0 + 3 < NQQ);

    float cg0, cg1, cg2, cg3;
    float C0 = pair_cost(a01, a23, a45, lga, T, &cg0);
    float C1 = pair_cost(b01, b23, b45, lgb, T, &cg1);
    float C2 = pair_cost(c01, c23, c45, lgc, T, &cg2);
    float C3 = pair_cost(d01, d23, d45, lgd, T, &cg3);
    if (!va) C0 = INFINITY;
    if (!vb) C1 = INFINITY;
    if (!vc) C2 = INFINITY;
    if (!vd) C3 = INFINITY;

    // ---- local reductions (ascending strict < => lowest local q on tie) ----
    float bestC = C0; int bestj = 0;
    if (C1 < bestC) { bestC = C1; bestj = 1; }
    if (C2 < bestC) { bestC = C2; bestj = 2; }
    if (C3 < bestC) { bestC = C3; bestj = 3; }
    float gx = va ? cg0 : -INFINITY;
    float gn = va ? cg0 :  INFINITY;
    if (vb) { gx = fmaxf(gx, cg1); gn = fminf(gn, cg1); }
    if (vc) { gx = fmaxf(gx, cg2); gn = fminf(gn, cg2); }
    if (vd) { gx = fmaxf(gx, cg3); gn = fminf(gn, cg3); }

    // ---- 3-step butterfly over the 8-lane group ----
    float m = bestC;
#pragma unroll
    for (int s = 4; s >= 1; s >>= 1) {
        m  = fminf(m,  __shfl_xor(m,  s, 8));
        gx = fmaxf(gx, __shfl_xor(gx, s, 8));
        gn = fminf(gn, __shfl_xor(gn, s, 8));
    }

    // ---- argmin winner via ballot: lowest lane w/ local min == m ----
    const unsigned long long bal = __ballot(bestC == m);
    const int gbase  = (threadIdx.x & 63) & ~7;
    const unsigned int gbits = (unsigned int)(bal >> gbase) & 0xFFu;
    const int winner = __ffs(gbits) - 1;
    const bool mine  = (winner == l);

    // ---- outputs: plain coalesced stores (NT stores caused 3x write amplification) ----
    float* om = out_matches + (size_t)p * NQQ + q0;
    float* os = out_soft    + (size_t)p * NQQ + q0;
    const float inv = frcp(gn - gx);
    if (va) { om[0] = (pres && mine && bestj == 0) ? 1.0f : 0.0f;
              os[0] = pres ? fmaxf((cg0 - gx) * inv, 0.0f) : -1.0f; }
    if (vb) { om[1] = (pres && mine && bestj == 1) ? 1.0f : 0.0f;
              os[1] = pres ? fmaxf((cg1 - gx) * inv, 0.0f) : -1.0f; }
    if (vc) { om[2] = (pres && mine && bestj == 2) ? 1.0f : 0.0f;
              os[2] = pres ? fmaxf((cg2 - gx) * inv, 0.0f) : -1.0f; }
    if (vd) { om[3] = (pres && mine && bestj == 3) ? 1.0f : 0.0f;
              os[3] = pres ? fmaxf((cg3 - gx) * inv, 0.0f) : -1.0f; }
}

extern "C" void kernel_launch(void* const* d_in, const int* in_sizes, int n_in,
                              void* d_out, int out_size, void* d_ws, size_t ws_size,
                              hipStream_t stream) {
    const float* logits  = (const float*)d_in[0];
    const float* boxes   = (const float*)d_in[1];
    const float* tboxes  = (const float*)d_in[2];
    const int*   presnt  = (const int*)d_in[3];

    float* out = (float*)d_out;
    float* out_matches = out;
    float* out_soft    = out + (size_t)NPAIR * NQQ;

    dim3 block(256);
    dim3 grid((NPAIR * 8) / 256);   // exactly 5120 blocks
    matcher_kernel<<<grid, block, 0, stream>>>(logits, boxes, tboxes, presnt,
                                               out_matches, out_soft);
}

// Round 7
// 33.470 us; speedup vs baseline: 1.7064x; 1.0426x over previous
//
#include <hip/hip_runtime.h>
#include <hip/hip_bf16.h>
#include <math.h>

#define NCC 20
#define NQQ 27
#define BSZ 8192
#define NPAIR (BSZ * NCC)
#define PPB 32            // pairs per 256-thread block (8 lanes/pair)

__device__ __forceinline__ float frcp(float x) { return __builtin_amdgcn_rcpf(x); }

struct Tgt {
    float tc0, tc1, tc2, tw, th, td;
    float tl0, tl1, tl2, th0, th1, th2, vol;
};

__device__ __forceinline__ Tgt make_tgt(float2 t01, float2 t23, float2 t45) {
    Tgt T;
    T.tc0 = t01.x; T.tc1 = t01.y; T.tc2 = t23.x;
    T.tw  = t23.y; T.th  = t45.x; T.td  = t45.y;
    T.tl0 = T.tc0 - 0.5f * T.tw; T.tl1 = T.tc1 - 0.5f * T.th; T.tl2 = T.tc2 - 0.5f * T.td;
    T.th0 = T.tc0 + 0.5f * T.tw; T.th1 = T.tc1 + 0.5f * T.th; T.th2 = T.tc2 + 0.5f * T.td;
    T.vol = (T.th0 - T.tl0) * (T.th1 - T.tl1) * (T.th2 - T.tl2);
    return T;
}

__device__ __forceinline__ float pair_cost(float2 b01, float2 b23, float2 b45,
                                           float lg, const Tgt& T, float* cg) {
    const float bc0 = b01.x, bc1 = b01.y, bc2 = b23.x;
    const float bw  = b23.y, bh  = b45.x, bd  = b45.y;

    const float cost_class = -frcp(1.0f + __expf(-lg));

    const float cost_bbox =
        fabsf(bc0 - T.tc0) + fabsf(bc1 - T.tc1) + fabsf(bc2 - T.tc2) +
        fabsf(bw  - T.tw ) + fabsf(bh  - T.th ) + fabsf(bd  - T.td );

    const float cc0 = fmaxf(bc0, 0.0f), cc1 = fmaxf(bc1, 0.0f), cc2 = fmaxf(bc2, 0.0f);
    const float cw  = fmaxf(bw , 0.0f), ch  = fmaxf(bh , 0.0f), cd  = fmaxf(bd , 0.0f);
    const float pl0 = cc0 - 0.5f * cw, pl1 = cc1 - 0.5f * ch, pl2 = cc2 - 0.5f * cd;
    const float ph0 = cc0 + 0.5f * cw, ph1 = cc1 + 0.5f * ch, ph2 = cc2 + 0.5f * cd;
    const float vol_p = (ph0 - pl0) * (ph1 - pl1) * (ph2 - pl2);

    const float i0 = fmaxf(fminf(ph0, T.th0) - fmaxf(pl0, T.tl0), 0.0f);
    const float i1 = fmaxf(fminf(ph1, T.th1) - fmaxf(pl1, T.tl1), 0.0f);
    const float i2 = fmaxf(fminf(ph2, T.th2) - fmaxf(pl2, T.tl2), 0.0f);
    const float inter = i0 * i1 * i2;
    const float uni   = vol_p + T.vol - inter;
    const float iou   = inter * frcp(uni);

    const float h0 = fmaxf(fmaxf(ph0, T.th0) - fminf(pl0, T.tl0), 0.0f);
    const float h1 = fmaxf(fmaxf(ph1, T.th1) - fminf(pl1, T.tl1), 0.0f);
    const float h2 = fmaxf(fmaxf(ph2, T.th2) - fminf(pl2, T.tl2), 0.0f);
    const float hull = h0 * h1 * h2;

    const float giou = iou - (hull - uni) * frcp(hull);
    *cg = -giou;
    return 5.0f * cost_bbox + 2.0f * cost_class + 2.0f * (-giou);
}

__global__ __launch_bounds__(256, 6) void matcher_kernel(
    const float* __restrict__ logits,
    const float* __restrict__ boxes,
    const float* __restrict__ tboxes,
    const int*   __restrict__ present,
    float* __restrict__ out_matches,
    float* __restrict__ out_soft)
{
    __shared__ float sBox[PPB * 162];   // 20736 B, contiguous image of 32 pairs' boxes
    __shared__ float sLog[PPB * NQQ];   // 3456 B
    __shared__ float sTgt[PPB * 6];     // 768 B
    __shared__ int   sPres[PPB];        // 128 B

    const int tid = threadIdx.x;
    const size_t pairBase = (size_t)blockIdx.x * PPB;

    // ---- cooperative staging: ALL loads are lane-contiguous float4 ----
    {
        const float4* srcB = reinterpret_cast<const float4*>(boxes + pairBase * 162);
        float4* dstB = reinterpret_cast<float4*>(sBox);
#pragma unroll
        for (int i = 0; i < 5; ++i) dstB[i * 256 + tid] = srcB[i * 256 + tid];   // 1280
        if (tid < 16) dstB[1280 + tid] = srcB[1280 + tid];                        // 1296 total

        if (tid < 216) reinterpret_cast<float4*>(sLog)[tid] =
            reinterpret_cast<const float4*>(logits + pairBase * NQQ)[tid];
        if (tid < 48)  reinterpret_cast<float4*>(sTgt)[tid] =
            reinterpret_cast<const float4*>(tboxes + pairBase * 6)[tid];
        if (tid < PPB) sPres[tid] = present[pairBase + tid];
    }
    __syncthreads();

    // ---- compute: 8 lanes per pair, lane l handles queries 4l..4l+3 ----
    const int lp = tid >> 3;            // pair within block (0..31)
    const int l  = tid & 7;
    const int q0 = l * 4;
    const size_t p = pairBase + lp;

    const int qa = (q0 + 0 < NQQ) ? q0 + 0 : NQQ - 1;
    const int qb = (q0 + 1 < NQQ) ? q0 + 1 : NQQ - 1;
    const int qc = (q0 + 2 < NQQ) ? q0 + 2 : NQQ - 1;
    const int qd = (q0 + 3 < NQQ) ? q0 + 3 : NQQ - 1;

    const float* bp = sBox + lp * 162;
    float2 a01 = *reinterpret_cast<const float2*>(bp + qa * 6 + 0);
    float2 a23 = *reinterpret_cast<const float2*>(bp + qa * 6 + 2);
    float2 a45 = *reinterpret_cast<const float2*>(bp + qa * 6 + 4);
    float2 b01 = *reinterpret_cast<const float2*>(bp + qb * 6 + 0);
    float2 b23 = *reinterpret_cast<const float2*>(bp + qb * 6 + 2);
    float2 b45 = *reinterpret_cast<const float2*>(bp + qb * 6 + 4);
    float2 c01 = *reinterpret_cast<const float2*>(bp + qc * 6 + 0);
    float2 c23 = *reinterpret_cast<const float2*>(bp + qc * 6 + 2);
    float2 c45 = *reinterpret_cast<const float2*>(bp + qc * 6 + 4);
    float2 d01 = *reinterpret_cast<const float2*>(bp + qd * 6 + 0);
    float2 d23 = *reinterpret_cast<const float2*>(bp + qd * 6 + 2);
    float2 d45 = *reinterpret_cast<const float2*>(bp + qd * 6 + 4);
    const float* lpg = sLog + lp * NQQ;
    const float lga = lpg[qa], lgb = lpg[qb], lgc = lpg[qc], lgd = lpg[qd];
    const float* tp = sTgt + lp * 6;
    float2 t01 = *reinterpret_cast<const float2*>(tp + 0);
    float2 t23 = *reinterpret_cast<const float2*>(tp + 2);
    float2 t45 = *reinterpret_cast<const float2*>(tp + 4);
    const int pres = sPres[lp];

    const Tgt T = make_tgt(t01, t23, t45);

    const bool va = (q0 + 0 < NQQ), vb = (q0 + 1 < NQQ),
               vc = (q0 + 2 < NQQ), vd = (q0 + 3 < NQQ);

    float cg0, cg1, cg2, cg3;
    float C0 = pair_cost(a01, a23, a45, lga, T, &cg0);
    float C1 = pair_cost(b01, b23, b45, lgb, T, &cg1);
    float C2 = pair_cost(c01, c23, c45, lgc, T, &cg2);
    float C3 = pair_cost(d01, d23, d45, lgd, T, &cg3);
    if (!va) C0 = INFINITY;
    if (!vb) C1 = INFINITY;
    if (!vc) C2 = INFINITY;
    if (!vd) C3 = INFINITY;

    // ---- local argmin (strict < => lowest q on tie) + min/max of cg ----
    float bestC = C0; int bestj = 0;
    if (C1 < bestC) { bestC = C1; bestj = 1; }
    if (C2 < bestC) { bestC = C2; bestj = 2; }
    if (C3 < bestC) { bestC = C3; bestj = 3; }
    float gx = va ? cg0 : -INFINITY;
    float gn = va ? cg0 :  INFINITY;
    if (vb) { gx = fmaxf(gx, cg1); gn = fminf(gn, cg1); }
    if (vc) { gx = fmaxf(gx, cg2); gn = fminf(gn, cg2); }
    if (vd) { gx = fmaxf(gx, cg3); gn = fminf(gn, cg3); }

    // ---- 3-step butterfly over 8-lane group ----
    float m = bestC;
#pragma unroll
    for (int s = 4; s >= 1; s >>= 1) {
        m  = fminf(m,  __shfl_xor(m,  s, 8));
        gx = fmaxf(gx, __shfl_xor(gx, s, 8));
        gn = fminf(gn, __shfl_xor(gn, s, 8));
    }

    // ---- winner via ballot: lowest lane whose local min == group min ----
    const unsigned long long bal = __ballot(bestC == m);
    const int gbase  = (tid & 63) & ~7;
    const unsigned int gbits = (unsigned int)(bal >> gbase) & 0xFFu;
    const int winner = __ffs(gbits) - 1;
    const bool mine  = (winner == l);

    // ---- outputs: plain coalesced stores ----
    float* om = out_matches + p * NQQ + q0;
    float* os = out_soft    + p * NQQ + q0;
    const float inv = frcp(gn - gx);
    if (va) { om[0] = (pres && mine && bestj == 0) ? 1.0f : 0.0f;
              os[0] = pres ? fmaxf((cg0 - gx) * inv, 0.0f) : -1.0f; }
    if (vb) { om[1] = (pres && mine && bestj == 1) ? 1.0f : 0.0f;
              os[1] = pres ? fmaxf((cg1 - gx) * inv, 0.0f) : -1.0f; }
    if (vc) { om[2] = (pres && mine && bestj == 2) ? 1.0f : 0.0f;
              os[2] = pres ? fmaxf((cg2 - gx) * inv, 0.0f) : -1.0f; }
    if (vd) { om[3] = (pres && mine && bestj == 3) ? 1.0f : 0.0f;
              os[3] = pres ? fmaxf((cg3 - gx) * inv, 0.0f) : -1.0f; }
}

extern "C" void kernel_launch(void* const* d_in, const int* in_sizes, int n_in,
                              void* d_out, int out_size, void* d_ws, size_t ws_size,
                              hipStream_t stream) {
    const float* logits  = (const float*)d_in[0];
    const float* boxes   = (const float*)d_in[1];
    const float* tboxes  = (const float*)d_in[2];
    const int*   presnt  = (const int*)d_in[3];

    float* out = (float*)d_out;
    float* out_matches = out;
    float* out_soft    = out + (size_t)NPAIR * NQQ;

    dim3 block(256);
    dim3 grid(NPAIR / PPB);   // exactly 5120 blocks
    matcher_kernel<<<grid, block, 0, stream>>>(logits, boxes, tboxes, presnt,
                                               out_matches, out_soft);
}

// Round 8
// 32.657 us; speedup vs baseline: 1.7489x; 1.0249x over previous
//
#include <hip/hip_runtime.h>
#include <hip/hip_bf16.h>
#include <math.h>

#define NCC 20
#define NQQ 27
#define BSZ 8192
#define NPAIR (BSZ * NCC)
#define PPB 32            // pairs per 256-thread block (8 lanes/pair)

__device__ __forceinline__ float frcp(float x) { return __builtin_amdgcn_rcpf(x); }

struct Tgt {
    float tc0, tc1, tc2, tw, th, td;
    float tl0, tl1, tl2, th0, th1, th2, vol;
};

__device__ __forceinline__ Tgt make_tgt(float2 t01, float2 t23, float2 t45) {
    Tgt T;
    T.tc0 = t01.x; T.tc1 = t01.y; T.tc2 = t23.x;
    T.tw  = t23.y; T.th  = t45.x; T.td  = t45.y;
    T.tl0 = T.tc0 - 0.5f * T.tw; T.tl1 = T.tc1 - 0.5f * T.th; T.tl2 = T.tc2 - 0.5f * T.td;
    T.th0 = T.tc0 + 0.5f * T.tw; T.th1 = T.tc1 + 0.5f * T.th; T.th2 = T.tc2 + 0.5f * T.td;
    T.vol = (T.th0 - T.tl0) * (T.th1 - T.tl1) * (T.th2 - T.tl2);
    return T;
}

__device__ __forceinline__ float pair_cost(float2 b01, float2 b23, float2 b45,
                                           float lg, const Tgt& T, float* cg) {
    const float bc0 = b01.x, bc1 = b01.y, bc2 = b23.x;
    const float bw  = b23.y, bh  = b45.x, bd  = b45.y;

    const float cost_class = -frcp(1.0f + __expf(-lg));

    const float cost_bbox =
        fabsf(bc0 - T.tc0) + fabsf(bc1 - T.tc1) + fabsf(bc2 - T.tc2) +
        fabsf(bw  - T.tw ) + fabsf(bh  - T.th ) + fabsf(bd  - T.td );

    const float cc0 = fmaxf(bc0, 0.0f), cc1 = fmaxf(bc1, 0.0f), cc2 = fmaxf(bc2, 0.0f);
    const float cw  = fmaxf(bw , 0.0f), ch  = fmaxf(bh , 0.0f), cd  = fmaxf(bd , 0.0f);
    const float pl0 = cc0 - 0.5f * cw, pl1 = cc1 - 0.5f * ch, pl2 = cc2 - 0.5f * cd;
    const float ph0 = cc0 + 0.5f * cw, ph1 = cc1 + 0.5f * ch, ph2 = cc2 + 0.5f * cd;
    const float vol_p = (ph0 - pl0) * (ph1 - pl1) * (ph2 - pl2);

    const float i0 = fmaxf(fminf(ph0, T.th0) - fmaxf(pl0, T.tl0), 0.0f);
    const float i1 = fmaxf(fminf(ph1, T.th1) - fmaxf(pl1, T.tl1), 0.0f);
    const float i2 = fmaxf(fminf(ph2, T.th2) - fmaxf(pl2, T.tl2), 0.0f);
    const float inter = i0 * i1 * i2;
    const float uni   = vol_p + T.vol - inter;
    const float iou   = inter * frcp(uni);

    const float h0 = fmaxf(fmaxf(ph0, T.th0) - fminf(pl0, T.tl0), 0.0f);
    const float h1 = fmaxf(fmaxf(ph1, T.th1) - fminf(pl1, T.tl1), 0.0f);
    const float h2 = fmaxf(fmaxf(ph2, T.th2) - fminf(pl2, T.tl2), 0.0f);
    const float hull = h0 * h1 * h2;

    const float giou = iou - (hull - uni) * frcp(hull);
    *cg = -giou;
    return 5.0f * cost_bbox + 2.0f * cost_class + 2.0f * (-giou);
}

__global__ __launch_bounds__(256, 6) void matcher_kernel(
    const float* __restrict__ logits,
    const float* __restrict__ boxes,
    const float* __restrict__ tboxes,
    const int*   __restrict__ present,
    float* __restrict__ out_matches,
    float* __restrict__ out_soft)
{
    __shared__ float sBox[PPB * 162];   // 20736 B; REUSED for output staging after compute
    __shared__ float sLog[PPB * NQQ];   // 3456 B
    __shared__ float sTgt[PPB * 6];     // 768 B
    __shared__ int   sPres[PPB];        // 128 B

    const int tid = threadIdx.x;
    const size_t pairBase = (size_t)blockIdx.x * PPB;

    // ---- cooperative staging: ALL loads are lane-contiguous float4 ----
    {
        const float4* srcB = reinterpret_cast<const float4*>(boxes + pairBase * 162);
        float4* dstB = reinterpret_cast<float4*>(sBox);
#pragma unroll
        for (int i = 0; i < 5; ++i) dstB[i * 256 + tid] = srcB[i * 256 + tid];   // 1280
        if (tid < 16) dstB[1280 + tid] = srcB[1280 + tid];                        // 1296 total

        if (tid < 216) reinterpret_cast<float4*>(sLog)[tid] =
            reinterpret_cast<const float4*>(logits + pairBase * NQQ)[tid];
        if (tid < 48)  reinterpret_cast<float4*>(sTgt)[tid] =
            reinterpret_cast<const float4*>(tboxes + pairBase * 6)[tid];
        if (tid < PPB) sPres[tid] = present[pairBase + tid];
    }
    __syncthreads();

    // ---- compute: 8 lanes per pair, lane l handles queries 4l..4l+3 ----
    const int lp = tid >> 3;            // pair within block (0..31)
    const int l  = tid & 7;
    const int q0 = l * 4;

    const int qa = (q0 + 0 < NQQ) ? q0 + 0 : NQQ - 1;
    const int qb = (q0 + 1 < NQQ) ? q0 + 1 : NQQ - 1;
    const int qc = (q0 + 2 < NQQ) ? q0 + 2 : NQQ - 1;
    const int qd = (q0 + 3 < NQQ) ? q0 + 3 : NQQ - 1;

    const float* bp = sBox + lp * 162;
    float2 a01 = *reinterpret_cast<const float2*>(bp + qa * 6 + 0);
    float2 a23 = *reinterpret_cast<const float2*>(bp + qa * 6 + 2);
    float2 a45 = *reinterpret_cast<const float2*>(bp + qa * 6 + 4);
    float2 b01 = *reinterpret_cast<const float2*>(bp + qb * 6 + 0);
    float2 b23 = *reinterpret_cast<const float2*>(bp + qb * 6 + 2);
    float2 b45 = *reinterpret_cast<const float2*>(bp + qb * 6 + 4);
    float2 c01 = *reinterpret_cast<const float2*>(bp + qc * 6 + 0);
    float2 c23 = *reinterpret_cast<const float2*>(bp + qc * 6 + 2);
    float2 c45 = *reinterpret_cast<const float2*>(bp + qc * 6 + 4);
    float2 d01 = *reinterpret_cast<const float2*>(bp + qd * 6 + 0);
    float2 d23 = *reinterpret_cast<const float2*>(bp + qd * 6 + 2);
    float2 d45 = *reinterpret_cast<const float2*>(bp + qd * 6 + 4);
    const float* lpg = sLog + lp * NQQ;
    const float lga = lpg[qa], lgb = lpg[qb], lgc = lpg[qc], lgd = lpg[qd];
    const float* tp = sTgt + lp * 6;
    float2 t01 = *reinterpret_cast<const float2*>(tp + 0);
    float2 t23 = *reinterpret_cast<const float2*>(tp + 2);
    float2 t45 = *reinterpret_cast<const float2*>(tp + 4);
    const int pres = sPres[lp];

    const Tgt T = make_tgt(t01, t23, t45);

    const bool va = (q0 + 0 < NQQ), vb = (q0 + 1 < NQQ),
               vc = (q0 + 2 < NQQ), vd = (q0 + 3 < NQQ);

    float cg0, cg1, cg2, cg3;
    float C0 = pair_cost(a01, a23, a45, lga, T, &cg0);
    float C1 = pair_cost(b01, b23, b45, lgb, T, &cg1);
    float C2 = pair_cost(c01, c23, c45, lgc, T, &cg2);
    float C3 = pair_cost(d01, d23, d45, lgd, T, &cg3);
    if (!va) C0 = INFINITY;
    if (!vb) C1 = INFINITY;
    if (!vc) C2 = INFINITY;
    if (!vd) C3 = INFINITY;

    // ---- local argmin (strict < => lowest q on tie) + min/max of cg ----
    float bestC = C0; int bestj = 0;
    if (C1 < bestC) { bestC = C1; bestj = 1; }
    if (C2 < bestC) { bestC = C2; bestj = 2; }
    if (C3 < bestC) { bestC = C3; bestj = 3; }
    float gx = va ? cg0 : -INFINITY;
    float gn = va ? cg0 :  INFINITY;
    if (vb) { gx = fmaxf(gx, cg1); gn = fminf(gn, cg1); }
    if (vc) { gx = fmaxf(gx, cg2); gn = fminf(gn, cg2); }
    if (vd) { gx = fmaxf(gx, cg3); gn = fminf(gn, cg3); }

    // ---- 3-step butterfly over 8-lane group ----
    float m = bestC;
#pragma unroll
    for (int s = 4; s >= 1; s >>= 1) {
        m  = fminf(m,  __shfl_xor(m,  s, 8));
        gx = fmaxf(gx, __shfl_xor(gx, s, 8));
        gn = fminf(gn, __shfl_xor(gn, s, 8));
    }

    // ---- winner via ballot: lowest lane whose local min == group min ----
    const unsigned long long bal = __ballot(bestC == m);
    const int gbase  = (tid & 63) & ~7;
    const unsigned int gbits = (unsigned int)(bal >> gbase) & 0xFFu;
    const int winner = __ffs(gbits) - 1;
    const bool mine  = (winner == l);

    // ---- stage outputs in LDS (reuse sBox: all reads of it are done) ----
    __syncthreads();                         // everyone finished reading sBox/sLog/sTgt
    float* sOutM = sBox;                     // 864 floats
    float* sOutS = sBox + PPB * NQQ;         // 864 floats

    const float inv = frcp(gn - gx);
    float* smM = sOutM + lp * NQQ + q0;
    float* smS = sOutS + lp * NQQ + q0;
    if (va) { smM[0] = (pres && mine && bestj == 0) ? 1.0f : 0.0f;
              smS[0] = pres ? fmaxf((cg0 - gx) * inv, 0.0f) : -1.0f; }
    if (vb) { smM[1] = (pres && mine && bestj == 1) ? 1.0f : 0.0f;
              smS[1] = pres ? fmaxf((cg1 - gx) * inv, 0.0f) : -1.0f; }
    if (vc) { smM[2] = (pres && mine && bestj == 2) ? 1.0f : 0.0f;
              smS[2] = pres ? fmaxf((cg2 - gx) * inv, 0.0f) : -1.0f; }
    if (vd) { smM[3] = (pres && mine && bestj == 3) ? 1.0f : 0.0f;
              smS[3] = pres ? fmaxf((cg3 - gx) * inv, 0.0f) : -1.0f; }
    __syncthreads();

    // ---- fully-coalesced float4 stores: 216 per output array ----
    // block output chunk = PPB*NQQ*4 = 3456 B, base offset blockIdx*3456 (16B-aligned)
    if (tid < 216) {
        const float4 vM = reinterpret_cast<const float4*>(sOutM)[tid];
        const float4 vS = reinterpret_cast<const float4*>(sOutS)[tid];
        reinterpret_cast<float4*>(out_matches + pairBase * NQQ)[tid] = vM;
        reinterpret_cast<float4*>(out_soft    + pairBase * NQQ)[tid] = vS;
    }
}

extern "C" void kernel_launch(void* const* d_in, const int* in_sizes, int n_in,
                              void* d_out, int out_size, void* d_ws, size_t ws_size,
                              hipStream_t stream) {
    const float* logits  = (const float*)d_in[0];
    const float* boxes   = (const float*)d_in[1];
    const float* tboxes  = (const float*)d_in[2];
    const int*   presnt  = (const int*)d_in[3];

    float* out = (float*)d_out;
    float* out_matches = out;
    float* out_soft    = out + (size_t)NPAIR * NQQ;

    dim3 block(256);
    dim3 grid(NPAIR / PPB);   // exactly 5120 blocks
    matcher_kernel<<<grid, block, 0, stream>>>(logits, boxes, tboxes, presnt,
                                               out_matches, out_soft);
}

// Round 9
// 30.811 us; speedup vs baseline: 1.8537x; 1.0599x over previous
//
#include <hip/hip_runtime.h>
#include <hip/hip_bf16.h>
#include <math.h>

#define NCC 20
#define NQQ 27
#define BSZ 8192
#define NPAIR (BSZ * NCC)
#define PPB 32            // pairs per 256-thread block (8 lanes/pair)

typedef __attribute__((address_space(1))) const float gfloat;
typedef __attribute__((address_space(3))) float lfloat;

__device__ __forceinline__ float frcp(float x) { return __builtin_amdgcn_rcpf(x); }

struct Tgt {
    float tc0, tc1, tc2, tw, th, td;
    float tl0, tl1, tl2, th0, th1, th2, vol;
};

__device__ __forceinline__ Tgt make_tgt(float2 t01, float2 t23, float2 t45) {
    Tgt T;
    T.tc0 = t01.x; T.tc1 = t01.y; T.tc2 = t23.x;
    T.tw  = t23.y; T.th  = t45.x; T.td  = t45.y;
    T.tl0 = T.tc0 - 0.5f * T.tw; T.tl1 = T.tc1 - 0.5f * T.th; T.tl2 = T.tc2 - 0.5f * T.td;
    T.th0 = T.tc0 + 0.5f * T.tw; T.th1 = T.tc1 + 0.5f * T.th; T.th2 = T.tc2 + 0.5f * T.td;
    T.vol = (T.th0 - T.tl0) * (T.th1 - T.tl1) * (T.th2 - T.tl2);
    return T;
}

__device__ __forceinline__ float pair_cost(float2 b01, float2 b23, float2 b45,
                                           float lg, const Tgt& T, float* cg) {
    const float bc0 = b01.x, bc1 = b01.y, bc2 = b23.x;
    const float bw  = b23.y, bh  = b45.x, bd  = b45.y;

    const float cost_class = -frcp(1.0f + __expf(-lg));

    const float cost_bbox =
        fabsf(bc0 - T.tc0) + fabsf(bc1 - T.tc1) + fabsf(bc2 - T.tc2) +
        fabsf(bw  - T.tw ) + fabsf(bh  - T.th ) + fabsf(bd  - T.td );

    const float cc0 = fmaxf(bc0, 0.0f), cc1 = fmaxf(bc1, 0.0f), cc2 = fmaxf(bc2, 0.0f);
    const float cw  = fmaxf(bw , 0.0f), ch  = fmaxf(bh , 0.0f), cd  = fmaxf(bd , 0.0f);
    const float pl0 = cc0 - 0.5f * cw, pl1 = cc1 - 0.5f * ch, pl2 = cc2 - 0.5f * cd;
    const float ph0 = cc0 + 0.5f * cw, ph1 = cc1 + 0.5f * ch, ph2 = cc2 + 0.5f * cd;
    const float vol_p = (ph0 - pl0) * (ph1 - pl1) * (ph2 - pl2);

    const float i0 = fmaxf(fminf(ph0, T.th0) - fmaxf(pl0, T.tl0), 0.0f);
    const float i1 = fmaxf(fminf(ph1, T.th1) - fmaxf(pl1, T.tl1), 0.0f);
    const float i2 = fmaxf(fminf(ph2, T.th2) - fmaxf(pl2, T.tl2), 0.0f);
    const float inter = i0 * i1 * i2;
    const float uni   = vol_p + T.vol - inter;
    const float iou   = inter * frcp(uni);

    const float h0 = fmaxf(fmaxf(ph0, T.th0) - fminf(pl0, T.tl0), 0.0f);
    const float h1 = fmaxf(fmaxf(ph1, T.th1) - fminf(pl1, T.tl1), 0.0f);
    const float h2 = fmaxf(fmaxf(ph2, T.th2) - fminf(pl2, T.tl2), 0.0f);
    const float hull = h0 * h1 * h2;

    const float giou = iou - (hull - uni) * frcp(hull);
    *cg = -giou;
    return 5.0f * cost_bbox + 2.0f * cost_class + 2.0f * (-giou);
}

__global__ __launch_bounds__(256, 7) void matcher_kernel(
    const float* __restrict__ logits,
    const float* __restrict__ boxes,
    const float* __restrict__ tboxes,
    const int*   __restrict__ present,
    float* __restrict__ out_matches,
    float* __restrict__ out_soft)
{
    __shared__ float sBox[PPB * 162];   // 20736 B exactly -> 7 blocks/CU

    const int tid = threadIdx.x;
    const size_t pairBase = (size_t)blockIdx.x * PPB;
    const float* gB = boxes + pairBase * 162;

    // ---- box staging: async global->LDS, linear layout (wave-uniform base + lane*16) ----
#pragma unroll
    for (int i = 0; i < 5; ++i) {
        __builtin_amdgcn_global_load_lds(
            (gfloat*)(gB   + (size_t)(i * 256 + tid) * 4),
            (lfloat*)(sBox + (size_t)(i * 256 + tid) * 4),
            16, 0, 0);
    }
    if (tid < 16) {   // remainder 16 float4s via regular path
        reinterpret_cast<float4*>(sBox)[1280 + tid] =
            reinterpret_cast<const float4*>(gB)[1280 + tid];
    }

    // ---- small per-pair inputs: direct register loads, overlap with staging ----
    const int lp = tid >> 3;            // pair within block (0..31)
    const int l  = tid & 7;
    const int q0 = l * 4;
    const size_t p = pairBase + lp;

    const int qa = (q0 + 0 < NQQ) ? q0 + 0 : NQQ - 1;
    const int qb = (q0 + 1 < NQQ) ? q0 + 1 : NQQ - 1;
    const int qc = (q0 + 2 < NQQ) ? q0 + 2 : NQQ - 1;
    const int qd = (q0 + 3 < NQQ) ? q0 + 3 : NQQ - 1;

    const float* lpg = logits + p * NQQ;
    const float lga = lpg[qa], lgb = lpg[qb], lgc = lpg[qc], lgd = lpg[qd];
    const float* tp_ = tboxes + p * 6;
    float2 t01 = *reinterpret_cast<const float2*>(tp_ + 0);
    float2 t23 = *reinterpret_cast<const float2*>(tp_ + 2);
    float2 t45 = *reinterpret_cast<const float2*>(tp_ + 4);
    const int pres = present[p];

    __syncthreads();    // drains global_load_lds (vmcnt) + ds_writes

    // ---- compute: 8 lanes per pair, lane l handles queries 4l..4l+3 ----
    const float* bp = sBox + lp * 162;
    float2 a01 = *reinterpret_cast<const float2*>(bp + qa * 6 + 0);
    float2 a23 = *reinterpret_cast<const float2*>(bp + qa * 6 + 2);
    float2 a45 = *reinterpret_cast<const float2*>(bp + qa * 6 + 4);
    float2 b01 = *reinterpret_cast<const float2*>(bp + qb * 6 + 0);
    float2 b23 = *reinterpret_cast<const float2*>(bp + qb * 6 + 2);
    float2 b45 = *reinterpret_cast<const float2*>(bp + qb * 6 + 4);
    float2 c01 = *reinterpret_cast<const float2*>(bp + qc * 6 + 0);
    float2 c23 = *reinterpret_cast<const float2*>(bp + qc * 6 + 2);
    float2 c45 = *reinterpret_cast<const float2*>(bp + qc * 6 + 4);
    float2 d01 = *reinterpret_cast<const float2*>(bp + qd * 6 + 0);
    float2 d23 = *reinterpret_cast<const float2*>(bp + qd * 6 + 2);
    float2 d45 = *reinterpret_cast<const float2*>(bp + qd * 6 + 4);

    const Tgt T = make_tgt(t01, t23, t45);

    const bool va = (q0 + 0 < NQQ), vb = (q0 + 1 < NQQ),
               vc = (q0 + 2 < NQQ), vd = (q0 + 3 < NQQ);

    float cg0, cg1, cg2, cg3;
    float C0 = pair_cost(a01, a23, a45, lga, T, &cg0);
    float C1 = pair_cost(b01, b23, b45, lgb, T, &cg1);
    float C2 = pair_cost(c01, c23, c45, lgc, T, &cg2);
    float C3 = pair_cost(d01, d23, d45, lgd, T, &cg3);
    if (!va) C0 = INFINITY;
    if (!vb) C1 = INFINITY;
    if (!vc) C2 = INFINITY;
    if (!vd) C3 = INFINITY;

    // ---- local argmin (strict < => lowest q on tie) + min/max of cg ----
    float bestC = C0; int bestj = 0;
    if (C1 < bestC) { bestC = C1; bestj = 1; }
    if (C2 < bestC) { bestC = C2; bestj = 2; }
    if (C3 < bestC) { bestC = C3; bestj = 3; }
    float gx = va ? cg0 : -INFINITY;
    float gn = va ? cg0 :  INFINITY;
    if (vb) { gx = fmaxf(gx, cg1); gn = fminf(gn, cg1); }
    if (vc) { gx = fmaxf(gx, cg2); gn = fminf(gn, cg2); }
    if (vd) { gx = fmaxf(gx, cg3); gn = fminf(gn, cg3); }

    // ---- 3-step butterfly over 8-lane group ----
    float m = bestC;
#pragma unroll
    for (int s = 4; s >= 1; s >>= 1) {
        m  = fminf(m,  __shfl_xor(m,  s, 8));
        gx = fmaxf(gx, __shfl_xor(gx, s, 8));
        gn = fminf(gn, __shfl_xor(gn, s, 8));
    }

    // ---- winner via ballot: lowest lane whose local min == group min ----
    const unsigned long long bal = __ballot(bestC == m);
    const int gbase  = (tid & 63) & ~7;
    const unsigned int gbits = (unsigned int)(bal >> gbase) & 0xFFu;
    const int winner = __ffs(gbits) - 1;
    const bool mine  = (winner == l);

    // ---- stage outputs in LDS (reuse sBox: all reads of it are done) ----
    __syncthreads();
    float* sOutM = sBox;                     // 864 floats
    float* sOutS = sBox + PPB * NQQ;         // 864 floats

    const float inv = frcp(gn - gx);
    float* smM = sOutM + lp * NQQ + q0;
    float* smS = sOutS + lp * NQQ + q0;
    if (va) { smM[0] = (pres && mine && bestj == 0) ? 1.0f : 0.0f;
              smS[0] = pres ? fmaxf((cg0 - gx) * inv, 0.0f) : -1.0f; }
    if (vb) { smM[1] = (pres && mine && bestj == 1) ? 1.0f : 0.0f;
              smS[1] = pres ? fmaxf((cg1 - gx) * inv, 0.0f) : -1.0f; }
    if (vc) { smM[2] = (pres && mine && bestj == 2) ? 1.0f : 0.0f;
              smS[2] = pres ? fmaxf((cg2 - gx) * inv, 0.0f) : -1.0f; }
    if (vd) { smM[3] = (pres && mine && bestj == 3) ? 1.0f : 0.0f;
              smS[3] = pres ? fmaxf((cg3 - gx) * inv, 0.0f) : -1.0f; }
    __syncthreads();

    // ---- fully-coalesced float4 stores: 216 per output array ----
    if (tid < 216) {
        const float4 vM = reinterpret_cast<const float4*>(sOutM)[tid];
        const float4 vS = reinterpret_cast<const float4*>(sOutS)[tid];
        reinterpret_cast<float4*>(out_matches + pairBase * NQQ)[tid] = vM;
        reinterpret_cast<float4*>(out_soft    + pairBase * NQQ)[tid] = vS;
    }
}

extern "C" void kernel_launch(void* const* d_in, const int* in_sizes, int n_in,
                              void* d_out, int out_size, void* d_ws, size_t ws_size,
                              hipStream_t stream) {
    const float* logits  = (const float*)d_in[0];
    const float* boxes   = (const float*)d_in[1];
    const float* tboxes  = (const float*)d_in[2];
    const int*   presnt  = (const int*)d_in[3];

    float* out = (float*)d_out;
    float* out_matches = out;
    float* out_soft    = out + (size_t)NPAIR * NQQ;

    dim3 block(256);
    dim3 grid(NPAIR / PPB);   // exactly 5120 blocks
    matcher_kernel<<<grid, block, 0, stream>>>(logits, boxes, tboxes, presnt,
                                               out_matches, out_soft);
}